// Round 9
// baseline (801.723 us; speedup 1.0000x reference)
//
#include <hip/hip_runtime.h>

// Problem constants (fixed by the reference file).
#define T_LEN 8192
#define D_CH  2048
#define CC    128                 // chunks along T
#define L_C   (T_LEN / CC)        // 64 steps per chunk
#define NG    (D_CH / 256)        // 8 channel groups per chunk
#define NBLK  (CC * NG)           // 1024 blocks = 4/CU exactly

// v = z*v + x (x real), z complex.
__device__ __forceinline__ void step_real(float zre, float zim,
                                          float& vre, float& vim, float x) {
    float nre = fmaf(zre, vre, fmaf(-zim, vim, x));
    float nim = fmaf(zre, vim, zim * vre);
    vre = nre; vim = nim;
}

union F2U { float2 f2; unsigned long long u; };

// Single-pass chunked scan with decoupled lookback (rocPRIM pattern).
// Block b: chunk c = b>>3, channels d = (b&7)*256 + tid. x is read from HBM
// exactly ONCE (held in registers across the lookback).
template <bool ILV>
__global__ __launch_bounds__(256, 4) void k_scan1(const float* __restrict__ x,
                                                  const float* __restrict__ size_,
                                                  const float* __restrict__ theta_,
                                                  float2* __restrict__ agg,
                                                  float2* __restrict__ pref,
                                                  int* __restrict__ flags,
                                                  float* __restrict__ out) {
    const int b = blockIdx.x;
    const int c = b >> 3;
    const int g = b & (NG - 1);
    const int d = (g << 8) + threadIdx.x;

    // z and z^L (closed form; rL underflow -> exactly 0 is correct AND is the
    // early-exit lever in the lookback).
    const float e  = expf(size_[d]);
    const float th = theta_[d];
    float s, cs;
    const float r1 = expf(-e);
    sincosf(th, &s, &cs);
    const float zre = r1 * cs, zim = r1 * s;
    const float rL = expf(-(float)L_C * e);
    sincosf((float)L_C * th, &s, &cs);
    const float zLre = rL * cs, zLim = rL * s;

    // Load the chunk into registers (64 independent loads in flight).
    const float* xp = x + (size_t)c * L_C * D_CH + d;
    float xa[L_C];
#pragma unroll
    for (int k = 0; k < L_C; ++k)
        xa[k] = xp[(size_t)k * D_CH];

    // Local scan from v=0 -> aggregate.
    float are = 0.f, aim = 0.f;
#pragma unroll
    for (int k = 0; k < L_C; ++k)
        step_real(zre, zim, are, aim, xa[k]);

    const size_t slot = (size_t)c * D_CH + d;
    F2U pa; pa.f2 = make_float2(are, aim);
    __hip_atomic_store((unsigned long long*)&agg[slot], pa.u,
                       __ATOMIC_RELAXED, __HIP_MEMORY_SCOPE_AGENT);

    float cre = 0.f, cim = 0.f;                 // carry INTO this chunk
    if (c == 0) {
        __hip_atomic_store((unsigned long long*)&pref[slot], pa.u,
                           __ATOMIC_RELAXED, __HIP_MEMORY_SCOPE_AGENT);
        __threadfence();
        __syncthreads();                         // drains vmem; all data out
        if (threadIdx.x == 0)
            __hip_atomic_store(&flags[b], 2, __ATOMIC_RELEASE,
                               __HIP_MEMORY_SCOPE_AGENT);
    } else {
        __threadfence();
        __syncthreads();
        if (threadIdx.x == 0)
            __hip_atomic_store(&flags[b], 1, __ATOMIC_RELEASE,
                               __HIP_MEMORY_SCOPE_AGENT);

        // Decoupled lookback. carry = sum_{j<c} mult_j * agg_j, mult *= z^L
        // per hop; shortcut on a published inclusive prefix. Per-thread early
        // exit when mult underflows to exactly 0 (depth ~2-6 in practice).
        float mre = 1.f, mim = 0.f;
        for (int j = c - 1; j >= 0; --j) {
            if (mre == 0.f && mim == 0.f) break;     // no further dependence
            int fj;
            do {
                fj = __hip_atomic_load(&flags[j * NG + g], __ATOMIC_ACQUIRE,
                                       __HIP_MEMORY_SCOPE_AGENT);
                if (fj == 0) __builtin_amdgcn_s_sleep(1);
            } while (fj == 0);
            const size_t js = (size_t)j * D_CH + d;
            F2U pv;
            if (fj == 2) {
                pv.u = __hip_atomic_load((unsigned long long*)&pref[js],
                                         __ATOMIC_RELAXED, __HIP_MEMORY_SCOPE_AGENT);
                cre = fmaf(mre, pv.f2.x, fmaf(-mim, pv.f2.y, cre));
                cim = fmaf(mre, pv.f2.y, fmaf( mim, pv.f2.x, cim));
                break;                                // prefix closes the sum
            } else {
                pv.u = __hip_atomic_load((unsigned long long*)&agg[js],
                                         __ATOMIC_RELAXED, __HIP_MEMORY_SCOPE_AGENT);
                cre = fmaf(mre, pv.f2.x, fmaf(-mim, pv.f2.y, cre));
                cim = fmaf(mre, pv.f2.y, fmaf( mim, pv.f2.x, cim));
                float nre = mre * zLre - mim * zLim;  // mult *= z^L
                float nim = fmaf(mre, zLim, mim * zLre);
                mre = nre; mim = nim;
            }
        }

        // Inclusive prefix of this chunk: P_c = agg_c + z^L * carry.
        F2U pp;
        pp.f2.x = fmaf(zLre, cre, fmaf(-zLim, cim, are));
        pp.f2.y = fmaf(zLre, cim, fmaf( zLim, cre, aim));
        __hip_atomic_store((unsigned long long*)&pref[slot], pp.u,
                           __ATOMIC_RELAXED, __HIP_MEMORY_SCOPE_AGENT);
        __threadfence();
        __syncthreads();
        if (threadIdx.x == 0)
            __hip_atomic_store(&flags[b], 2, __ATOMIC_RELEASE,
                               __HIP_MEMORY_SCOPE_AGENT);
    }

    // Replay from registers seeded with the carry; nontemporal stream out.
    float vre = cre, vim = cim;
    if (ILV) {
        float2* o2 = (float2*)out + (size_t)c * L_C * D_CH + d;
#pragma unroll
        for (int k = 0; k < L_C; ++k) {
            step_real(zre, zim, vre, vim, xa[k]);
            __builtin_nontemporal_store(vre, &o2[(size_t)k * D_CH].x);
            __builtin_nontemporal_store(vim, &o2[(size_t)k * D_CH].y);
        }
    } else {
        float* o = out + (size_t)c * L_C * D_CH + d;
#pragma unroll
        for (int k = 0; k < L_C; ++k) {
            step_real(zre, zim, vre, vim, xa[k]);
            __builtin_nontemporal_store(vre, &o[(size_t)k * D_CH]);
        }
    }
}

extern "C" void kernel_launch(void* const* d_in, const int* in_sizes, int n_in,
                              void* d_out, int out_size, void* d_ws, size_t ws_size,
                              hipStream_t stream) {
    const float* x  = (const float*)d_in[0];
    const float* sz = (const float*)d_in[1];
    const float* th = (const float*)d_in[2];
    float* out = (float*)d_out;

    char* ws = (char*)d_ws;
    float2* agg   = (float2*)(ws);                       // 2 MB
    float2* pref  = (float2*)(ws + (size_t)2 * 1024 * 1024);  // 2 MB
    int*    flags = (int*)   (ws + (size_t)4 * 1024 * 1024);  // 4 KB

    // Zero the lookback flags (ws is re-poisoned 0xAA before every replay).
    hipMemsetAsync(flags, 0, NBLK * sizeof(int), stream);

    const bool realOnly = (out_size == T_LEN * D_CH);
    if (realOnly)
        k_scan1<false><<<dim3(NBLK), dim3(256), 0, stream>>>(x, sz, th, agg,
                                                             pref, flags, out);
    else
        k_scan1<true><<<dim3(NBLK), dim3(256), 0, stream>>>(x, sz, th, agg,
                                                            pref, flags, out);
}

// Round 11
// 127.853 us; speedup vs baseline: 6.2707x; 6.2707x over previous
//
#include <hip/hip_runtime.h>

// Problem constants (fixed by the reference file).
#define T_LEN 8192
#define D_CH  2048
#define CC    128                 // chunks along T
#define L_C   (T_LEN / CC)        // 64 steps per chunk

// v = z*v + x (x real), z complex.
__device__ __forceinline__ void step_real(float zre, float zim,
                                          float& vre, float& vim, float x) {
    float nre = fmaf(zre, vre, fmaf(-zim, vim, x));
    float nim = fmaf(zre, vim, zim * vre);
    vre = nre; vim = nim;
}

__device__ __forceinline__ void load_z(const float* __restrict__ size_,
                                       const float* __restrict__ theta_,
                                       int d, float& zre, float& zim) {
    float e = expf(size_[d]);
    float r = expf(-e);
    float s, c;
    sincosf(theta_[d], &s, &c);
    zre = r * c;
    zim = r * s;
}

// Kernel 1: per (chunk, channel) local scan from v=0; publish ONLY the
// chunk-final complex value. Pure 64 MB coalesced read.
__global__ __launch_bounds__(256) void k_sums(const float* __restrict__ x,
                                              const float* __restrict__ size_,
                                              const float* __restrict__ theta_,
                                              float2* __restrict__ sums) {
    const int d = blockIdx.x * 256 + threadIdx.x;
    const int c = blockIdx.y;
    float zre, zim;
    load_z(size_, theta_, d, zre, zim);

    const float* xp = x + (size_t)c * L_C * D_CH + d;
    float vre = 0.f, vim = 0.f;
#pragma unroll 16
    for (int k = 0; k < L_C; ++k)
        step_real(zre, zim, vre, vim, xp[(size_t)k * D_CH]);
    sums[c * D_CH + d] = make_float2(vre, vim);
}

// Kernel 2: block (c) computes its own carry prefix BACKWARD over
// sums[c-1 .. 0] with multiplier mult *= z^L per hop. mult underflows to
// exactly 0 within ~1-3 batches of 16 for every channel, so a wave-uniform
// break bounds the work (exact arithmetic: dropped terms are exactly zero).
// Then scans its chunk seeded with the carry, re-reading x (L3-warm from k1),
// streaming the output with nontemporal stores.
template <bool ILV>
__global__ __launch_bounds__(256) void k_scan(const float* __restrict__ x,
                                              const float* __restrict__ size_,
                                              const float* __restrict__ theta_,
                                              const float2* __restrict__ sums,
                                              float* __restrict__ out) {
    const int d = blockIdx.x * 256 + threadIdx.x;
    const int c = blockIdx.y;

    float zre, zim;
    load_z(size_, theta_, d, zre, zim);

    // z^L closed form (underflow of rL -> 0 is correct).
    float e  = expf(size_[d]);
    float rL = expf(-(float)L_C * e);
    float sL, cL;
    sincosf((float)L_C * theta_[d], &sL, &cL);
    const float zLre = rL * cL, zLim = rL * sL;

    // Backward prefix with early exit:
    // carry = sum_{j=c-1..0} mult_j * sums[j], mult_{c-1}=1, mult *= z^L.
    float cre = 0.f, cim = 0.f;
    float mre = 1.f, mim = 0.f;
    for (int j0 = c - 1; j0 >= 0; j0 -= 16) {          // c is block-uniform
        const int nb = (j0 + 1 < 16) ? (j0 + 1) : 16;  // block-uniform count
        float2 loc[16];
#pragma unroll
        for (int t = 0; t < 16; ++t)
            loc[t] = (t < nb) ? sums[(size_t)(j0 - t) * D_CH + d]
                              : make_float2(0.f, 0.f);
#pragma unroll
        for (int t = 0; t < 16; ++t) {
            if (t < nb) {                              // block-uniform branch
                cre = fmaf(mre, loc[t].x, fmaf(-mim, loc[t].y, cre));
                cim = fmaf(mre, loc[t].y, fmaf( mim, loc[t].x, cim));
                float nre = mre * zLre - mim * zLim;   // mult *= z^L
                float nim = fmaf(mre, zLim, mim * zLre);
                mre = nre; mim = nim;
            }
        }
        // Wave-uniform early exit once every lane's multiplier is exactly 0.
        if (__all(mre == 0.f && mim == 0.f)) break;
    }

    // Scan the chunk seeded with the carry; stream out (nontemporal).
    float vre = cre, vim = cim;
    const float* xp = x + (size_t)c * L_C * D_CH + d;
    if (ILV) {
        float2* o2 = (float2*)out + (size_t)c * L_C * D_CH + d;
#pragma unroll 16
        for (int k = 0; k < L_C; ++k) {
            step_real(zre, zim, vre, vim, xp[(size_t)k * D_CH]);
            __builtin_nontemporal_store(vre, &o2[(size_t)k * D_CH].x);
            __builtin_nontemporal_store(vim, &o2[(size_t)k * D_CH].y);
        }
    } else {
        float* o = out + (size_t)c * L_C * D_CH + d;
#pragma unroll 16
        for (int k = 0; k < L_C; ++k) {
            step_real(zre, zim, vre, vim, xp[(size_t)k * D_CH]);
            __builtin_nontemporal_store(vre, &o[(size_t)k * D_CH]);
        }
    }
}

extern "C" void kernel_launch(void* const* d_in, const int* in_sizes, int n_in,
                              void* d_out, int out_size, void* d_ws, size_t ws_size,
                              hipStream_t stream) {
    const float* x  = (const float*)d_in[0];
    const float* sz = (const float*)d_in[1];
    const float* th = (const float*)d_in[2];
    float2* sums = (float2*)d_ws;                 // CC * D_CH * 8 B = 2 MB
    float* out = (float*)d_out;
    const bool realOnly = (out_size == T_LEN * D_CH);

    dim3 blk(256);
    dim3 grid(D_CH / 256, CC);                    // 1024 blocks = 4/CU

    k_sums<<<grid, blk, 0, stream>>>(x, sz, th, sums);
    if (realOnly)
        k_scan<false><<<grid, blk, 0, stream>>>(x, sz, th, sums, out);
    else
        k_scan<true><<<grid, blk, 0, stream>>>(x, sz, th, sums, out);
}

// Round 12
// 127.246 us; speedup vs baseline: 6.3006x; 1.0048x over previous
//
#include <hip/hip_runtime.h>

// Problem constants (fixed by the reference file).
#define T_LEN 8192
#define D_CH  2048
#define CC    256                 // chunks along T  (A/B: was 128)
#define L_C   (T_LEN / CC)        // 32 steps per chunk

// v = z*v + x (x real), z complex.
__device__ __forceinline__ void step_real(float zre, float zim,
                                          float& vre, float& vim, float x) {
    float nre = fmaf(zre, vre, fmaf(-zim, vim, x));
    float nim = fmaf(zre, vim, zim * vre);
    vre = nre; vim = nim;
}

__device__ __forceinline__ void load_z(const float* __restrict__ size_,
                                       const float* __restrict__ theta_,
                                       int d, float& zre, float& zim) {
    float e = expf(size_[d]);
    float r = expf(-e);
    float s, c;
    sincosf(theta_[d], &s, &c);
    zre = r * c;
    zim = r * s;
}

// Kernel 1: per (chunk, channel) local scan from v=0; publish ONLY the
// chunk-final complex value. Pure 64 MB coalesced read.
__global__ __launch_bounds__(256) void k_sums(const float* __restrict__ x,
                                              const float* __restrict__ size_,
                                              const float* __restrict__ theta_,
                                              float2* __restrict__ sums) {
    const int d = blockIdx.x * 256 + threadIdx.x;
    const int c = blockIdx.y;
    float zre, zim;
    load_z(size_, theta_, d, zre, zim);

    const float* xp = x + (size_t)c * L_C * D_CH + d;
    float vre = 0.f, vim = 0.f;
#pragma unroll 16
    for (int k = 0; k < L_C; ++k)
        step_real(zre, zim, vre, vim, xp[(size_t)k * D_CH]);
    sums[c * D_CH + d] = make_float2(vre, vim);
}

// Kernel 2: block (c) computes its own carry prefix BACKWARD over
// sums[c-1 .. 0] with multiplier mult *= z^L per hop; mult underflows to
// exactly 0 within ~2-4 batches of 16 (exact arithmetic: dropped terms are
// exactly zero), wave-uniform break. Then scans its chunk seeded with the
// carry, re-reading x (L3-warm from k1), nontemporal-streaming the output.
template <bool ILV>
__global__ __launch_bounds__(256) void k_scan(const float* __restrict__ x,
                                              const float* __restrict__ size_,
                                              const float* __restrict__ theta_,
                                              const float2* __restrict__ sums,
                                              float* __restrict__ out) {
    const int d = blockIdx.x * 256 + threadIdx.x;
    const int c = blockIdx.y;

    float zre, zim;
    load_z(size_, theta_, d, zre, zim);

    // z^L closed form (underflow of rL -> 0 is correct).
    float e  = expf(size_[d]);
    float rL = expf(-(float)L_C * e);
    float sL, cL;
    sincosf((float)L_C * theta_[d], &sL, &cL);
    const float zLre = rL * cL, zLim = rL * sL;

    // Backward prefix with early exit:
    // carry = sum_{j=c-1..0} mult_j * sums[j], mult_{c-1}=1, mult *= z^L.
    float cre = 0.f, cim = 0.f;
    float mre = 1.f, mim = 0.f;
    for (int j0 = c - 1; j0 >= 0; j0 -= 16) {          // c is block-uniform
        const int nb = (j0 + 1 < 16) ? (j0 + 1) : 16;  // block-uniform count
        float2 loc[16];
#pragma unroll
        for (int t = 0; t < 16; ++t)
            loc[t] = (t < nb) ? sums[(size_t)(j0 - t) * D_CH + d]
                              : make_float2(0.f, 0.f);
#pragma unroll
        for (int t = 0; t < 16; ++t) {
            if (t < nb) {                              // block-uniform branch
                cre = fmaf(mre, loc[t].x, fmaf(-mim, loc[t].y, cre));
                cim = fmaf(mre, loc[t].y, fmaf( mim, loc[t].x, cim));
                float nre = mre * zLre - mim * zLim;   // mult *= z^L
                float nim = fmaf(mre, zLim, mim * zLre);
                mre = nre; mim = nim;
            }
        }
        // Wave-uniform early exit once every lane's multiplier is exactly 0.
        if (__all(mre == 0.f && mim == 0.f)) break;
    }

    // Scan the chunk seeded with the carry; stream out (nontemporal).
    float vre = cre, vim = cim;
    const float* xp = x + (size_t)c * L_C * D_CH + d;
    if (ILV) {
        float2* o2 = (float2*)out + (size_t)c * L_C * D_CH + d;
#pragma unroll 16
        for (int k = 0; k < L_C; ++k) {
            step_real(zre, zim, vre, vim, xp[(size_t)k * D_CH]);
            __builtin_nontemporal_store(vre, &o2[(size_t)k * D_CH].x);
            __builtin_nontemporal_store(vim, &o2[(size_t)k * D_CH].y);
        }
    } else {
        float* o = out + (size_t)c * L_C * D_CH + d;
#pragma unroll 16
        for (int k = 0; k < L_C; ++k) {
            step_real(zre, zim, vre, vim, xp[(size_t)k * D_CH]);
            __builtin_nontemporal_store(vre, &o[(size_t)k * D_CH]);
        }
    }
}

extern "C" void kernel_launch(void* const* d_in, const int* in_sizes, int n_in,
                              void* d_out, int out_size, void* d_ws, size_t ws_size,
                              hipStream_t stream) {
    const float* x  = (const float*)d_in[0];
    const float* sz = (const float*)d_in[1];
    const float* th = (const float*)d_in[2];
    float2* sums = (float2*)d_ws;                 // CC * D_CH * 8 B = 4 MB
    float* out = (float*)d_out;
    const bool realOnly = (out_size == T_LEN * D_CH);

    dim3 blk(256);
    dim3 grid(D_CH / 256, CC);                    // 2048 blocks = 8/CU

    k_sums<<<grid, blk, 0, stream>>>(x, sz, th, sums);
    if (realOnly)
        k_scan<false><<<grid, blk, 0, stream>>>(x, sz, th, sums, out);
    else
        k_scan<true><<<grid, blk, 0, stream>>>(x, sz, th, sums, out);
}